// Round 10
// baseline (524.002 us; speedup 1.0000x reference)
//
#include <hip/hip_runtime.h>
#include <hip/hip_bf16.h>
#include <stdint.h>

#define Bb 32
#define Tt 2048
#define Dd 1024   // D_IN = D_H = D_OUT

typedef float    f32x4 __attribute__((ext_vector_type(4)));
typedef _Float16 f16x8 __attribute__((ext_vector_type(8)));
typedef uint32_t u32;

// ---- ws layout (bytes) ----
// 0        w2_ws  [32][1024] f32  (2 * s.W_a)          128K
// 131072   a_ws   [32][2048] f32                       256K
// 393216   UNION: e_part [8 ob][32 b][2048 t] f32 (2M, k_e->k_sm)
//                 cpart  [32 tc][32 b][1024] f32 (4M, k_c1->k_c2)
// 4587520  U_ts   tiled fp16 U^T (see k_ut)            2M
#define WS_A     131072
#define WS_EP    393216
#define WS_UT    4587520

__device__ __forceinline__ void gll16(const void* g, const void* lds) {
  __builtin_amdgcn_global_load_lds(
      (const __attribute__((address_space(1))) u32*)(uintptr_t)g,
      (__attribute__((address_space(3))) u32*)(uint32_t)(uintptr_t)lds,
      16, 0, 0);
}

// ---------------- kernel 1: w2[b][o] = 2 * sum_i s[b][i] * W[i][o] ----------------
__global__ __launch_bounds__(256) void k_ws(const float* __restrict__ s,
                                            const float* __restrict__ W,
                                            float* __restrict__ w2_ws) {
  const int b = blockIdx.x >> 2;
  const int o = (blockIdx.x & 3) * 256 + threadIdx.x;
  __shared__ float s_sh[Dd];
#pragma unroll
  for (int j = 0; j < 4; ++j)
    s_sh[threadIdx.x + 256 * j] = s[b * Dd + threadIdx.x + 256 * j];
  __syncthreads();
  float acc = 0.f;
#pragma unroll 8
  for (int i = 0; i < Dd; ++i) acc += s_sh[i] * W[(size_t)i * Dd + o];
  w2_ws[b * Dd + o] = 2.f * acc;
}

// ------- kernel 2: build U_ts, tile-major linear-lane layout -------
// Tile (ob, ks) = 16KB at (ob*16+ks)*16384; element (o_l, k_l):
// byte = (k_l>>5)*8192 + (o_l>>6)*4096 + ((o_l>>4)&3)*1024
//        + (((k_l>>3)&3)*16 + (o_l&15))*16 + (k_l&7)*2
__global__ __launch_bounds__(256) void k_ut(const float* __restrict__ U,
                                            uint8_t* __restrict__ U_ts) {
  const int i0 = (blockIdx.x >> 4) * 64;   // k-tile
  const int o0 = (blockIdx.x & 15) * 64;   // o-tile
  __shared__ float tile[64][65];           // [o_loc][k_loc]
  const int tx = threadIdx.x & 63;
  const int ty = threadIdx.x >> 6;
#pragma unroll
  for (int jj = 0; jj < 16; ++jj)
    tile[tx][ty + 4 * jj] = U[(size_t)(i0 + ty + 4 * jj) * Dd + o0 + tx];
  __syncthreads();
#pragma unroll
  for (int it = 0; it < 2; ++it) {
    const int g  = it * 256 + threadIdx.x;  // 0..511
    const int ol = g & 63;
    const int kg = g >> 6;                  // 0..7
    const int o  = o0 + ol;
    const int k  = i0 + kg * 8;
    f16x8 r;
#pragma unroll
    for (int m = 0; m < 8; ++m) r[m] = (_Float16)tile[ol][kg * 8 + m];
    const int ob  = o >> 7, ks = k >> 6;
    const int o_l = o & 127, k_l = k & 63;
    const size_t byte = ((size_t)(ob * 16 + ks) << 14)
                      + (size_t)((k_l >> 5) * 8192 + (o_l >> 6) * 4096
                      + ((o_l >> 4) & 3) * 1024
                      + (((k_l >> 3) & 3) * 16 + (o_l & 15)) * 16);
    *(f16x8*)(U_ts + byte) = r;
  }
}

// ---------------- kernel 3: fused GEMM, pipelined + conflict-free B ----------------
// 128t x 128o per block, BK=64 x 16 steps, 4 waves (hw=o-half, tw=t-half),
// acc[4][4]. A dbuf via gll16 (next-step DMA overlaps compute; correctness via
// in-order vmcnt: cvt waits B-regs issued AFTER A's gll16). B: reg-stage f32->fp16,
// XOR-swizzled ds_write (t15 ^= tid&7) -> 0 write conflicts; reads XOR to match.
__global__ __launch_bounds__(256, 3) void k_e(const float* __restrict__ h,
                                              const uint8_t* __restrict__ U_ts,
                                              const float* __restrict__ w2_ws,
                                              const float* __restrict__ v_a,
                                              float* __restrict__ e_part) {
  const int blk = blockIdx.x;
  const int b   = blk >> 7;
  const int ob  = (blk >> 4) & 7;
  const int tb  = blk & 15;
  const int tid  = threadIdx.x;
  const int lane = tid & 63;
  const int w    = tid >> 6;
  const int hw   = w & 1;    // o-half
  const int tw   = w >> 1;   // t-half

  __shared__ __align__(16) uint8_t Al[2][16384];
  __shared__ __align__(16) uint8_t Bl[16384];
  __shared__ float w_sh[128], v_sh[128], exch[128];

  if (tid < 128) {
    w_sh[tid] = w2_ws[b * Dd + ob * 128 + tid];
    v_sh[tid] = v_a[ob * 128 + tid];
  }

  // B global-load / swizzled LDS-write addressing
  const float* hrow = h + ((size_t)(b * Tt + tb * 128 + (tid >> 3))) * Dd + (tid & 7) * 8;
  int baddr[4];
  {
    const int kk  = (tid & 7) >> 2;
    const int klo = (tid & 7) & 3;
    const int cw  = tid & 7;
#pragma unroll
    for (int j = 0; j < 4; ++j) {
      const int t_l = (tid >> 3) + 32 * j;
      baddr[j] = kk * 8192 + (t_l >> 6) * 4096 + ((t_l >> 4) & 3) * 1024
               + (klo * 16 + ((t_l & 15) ^ cw)) * 16;
    }
  }
  // B read slots (swizzle-matched): kk=0 and kk=1
  const int klo_r = lane >> 4;
  const int rs0 = (klo_r * 16 + ((lane & 15) ^ klo_r)) * 16;
  const int rs1 = (klo_r * 16 + ((lane & 15) ^ klo_r ^ 4)) * 16;
  const uint8_t* Ub = U_ts + ((size_t)(ob * 16) << 14);

  f32x4 acc[4][4] = {};
  f32x4 brA[8], brB[8];

  // prologue: A(0) DMA first, then B(0) regs (order matters for the vmcnt chain)
  {
    const uint8_t* As = Ub + (size_t)tid * 16;
    gll16(As,         &Al[0][w * 1024]);
    gll16(As + 4096,  &Al[0][w * 1024 + 4096]);
    gll16(As + 8192,  &Al[0][w * 1024 + 8192]);
    gll16(As + 12288, &Al[0][w * 1024 + 12288]);
  }
#pragma unroll
  for (int j = 0; j < 4; ++j) {
    const float* p = hrow + (size_t)j * 32 * Dd;
    brA[2 * j]     = *(const f32x4*)p;
    brA[2 * j + 1] = *(const f32x4*)(p + 4);
  }

#define STEP(KS, CUR, brC, brN)                                               \
  {                                                                           \
    __builtin_amdgcn_sched_barrier(0);                                        \
    __builtin_amdgcn_s_barrier();            /* B1: LDS free, no vmem drain */\
    __builtin_amdgcn_sched_barrier(0);                                        \
    if ((KS) + 1 < 16) {                     /* next-A DMA into other buf */  \
      const uint8_t* As = Ub + ((size_t)((KS) + 1) << 14) + (size_t)tid * 16; \
      gll16(As,         &Al[(CUR) ^ 1][w * 1024]);                            \
      gll16(As + 4096,  &Al[(CUR) ^ 1][w * 1024 + 4096]);                     \
      gll16(As + 8192,  &Al[(CUR) ^ 1][w * 1024 + 8192]);                     \
      gll16(As + 12288, &Al[(CUR) ^ 1][w * 1024 + 12288]);                    \
    }                                                                         \
    _Pragma("unroll")                        /* cvt waits brC -> A(KS) done */\
    for (int j = 0; j < 4; ++j) {                                             \
      f16x8 pk;                                                               \
      _Pragma("unroll")                                                       \
      for (int m2 = 0; m2 < 4; ++m2) {                                        \
        pk[m2]     = (_Float16)brC[2 * j][m2];                                \
        pk[4 + m2] = (_Float16)brC[2 * j + 1][m2];                            \
      }                                                                       \
      *(f16x8*)(Bl + baddr[j]) = pk;                                          \
    }                                                                         \
    if ((KS) + 1 < 16) {                     /* next-B loads, in flight */    \
      _Pragma("unroll")                                                       \
      for (int j = 0; j < 4; ++j) {                                           \
        const float* p = hrow + (size_t)j * 32 * Dd + ((KS) + 1) * 64;        \
        brN[2 * j]     = *(const f32x4*)p;                                    \
        brN[2 * j + 1] = *(const f32x4*)(p + 4);                              \
      }                                                                       \
    }                                                                         \
    asm volatile("s_waitcnt lgkmcnt(0)" ::: "memory");  /* ds_writes done */  \
    __builtin_amdgcn_sched_barrier(0);                                        \
    __builtin_amdgcn_s_barrier();                        /* B2 */             \
    __builtin_amdgcn_sched_barrier(0);                                        \
    _Pragma("unroll")                                                         \
    for (int kk = 0; kk < 2; ++kk) {                                          \
      f16x8 af[4], bf[4];                                                     \
      _Pragma("unroll")                                                       \
      for (int n = 0; n < 4; ++n)                                             \
        af[n] = *(const f16x8*)(&Al[CUR][0] + kk * 8192 + hw * 4096           \
                                + n * 1024 + lane * 16);                      \
      _Pragma("unroll")                                                       \
      for (int m = 0; m < 4; ++m)                                             \
        bf[m] = *(const f16x8*)(Bl + kk * 8192 + tw * 4096 + m * 1024         \
                                + (kk ? rs1 : rs0));                          \
      _Pragma("unroll")                                                       \
      for (int m = 0; m < 4; ++m)                                             \
        _Pragma("unroll")                                                     \
        for (int n = 0; n < 4; ++n)                                           \
          acc[m][n] = __builtin_amdgcn_mfma_f32_16x16x32_f16(af[n], bf[m],    \
                                                             acc[m][n], 0, 0, 0); \
    }                                                                         \
  }

#pragma unroll 1
  for (int ks2 = 0; ks2 < 8; ++ks2) {
    const int ks = ks2 * 2;
    STEP(ks,     0, brA, brB)
    STEP(ks + 1, 1, brB, brA)
  }
#undef STEP

  // epilogue (once per block): tanh + v-weight + reduce over o
  float ep[4] = {0.f, 0.f, 0.f, 0.f};
#pragma unroll
  for (int m = 0; m < 4; ++m)
#pragma unroll
    for (int n = 0; n < 4; ++n)
#pragma unroll
      for (int r = 0; r < 4; ++r) {
        const int o_loc = hw * 64 + n * 16 + ((lane >> 4) << 2) + r;
        const float x = __builtin_fmaf(acc[m][n][r], 2.f, w_sh[o_loc]);
        ep[m] += v_sh[o_loc] * (1.f - 2.f / (__expf(x) + 1.f));
      }
#pragma unroll
  for (int m = 0; m < 4; ++m) {
    ep[m] += __shfl_xor(ep[m], 16, 64);
    ep[m] += __shfl_xor(ep[m], 32, 64);
  }
  __syncthreads();
  if (hw == 1 && lane < 16) {
#pragma unroll
    for (int m = 0; m < 4; ++m) exch[tw * 64 + m * 16 + lane] = ep[m];
  }
  __syncthreads();
  if (hw == 0 && lane < 16) {
#pragma unroll
    for (int m = 0; m < 4; ++m) {
      const int t_loc = tw * 64 + m * 16 + lane;
      e_part[((size_t)(ob * Bb + b)) * Tt + tb * 128 + t_loc] = ep[m] + exch[t_loc];
    }
  }
}

// ---------------- kernel 4: reduce 8 o-partials + softmax over T per b ----------------
__global__ __launch_bounds__(256) void k_sm(const float* __restrict__ e_part,
                                            float* __restrict__ a_ws) {
  const int b = blockIdx.x;
  const int lane = threadIdx.x & 63;
  const int wv = threadIdx.x >> 6;
  __shared__ float red[8];
  float ev[8];
  float m = -1e30f;
#pragma unroll
  for (int j = 0; j < 8; ++j) {
    const int t = threadIdx.x + 256 * j;
    float sv = 0.f;
#pragma unroll
    for (int o = 0; o < 8; ++o) sv += e_part[((size_t)(o * Bb + b)) * Tt + t];
    ev[j] = sv;
    m = fmaxf(m, sv);
  }
#pragma unroll
  for (int sft = 1; sft < 64; sft <<= 1) m = fmaxf(m, __shfl_xor(m, sft, 64));
  if (lane == 0) red[wv] = m;
  __syncthreads();
  m = fmaxf(fmaxf(red[0], red[1]), fmaxf(red[2], red[3]));
  float sum = 0.f;
#pragma unroll
  for (int j = 0; j < 8; ++j) { ev[j] = __expf(ev[j] - m); sum += ev[j]; }
#pragma unroll
  for (int sft = 1; sft < 64; sft <<= 1) sum += __shfl_xor(sum, sft, 64);
  if (lane == 0) red[4 + wv] = sum;
  __syncthreads();
  const float inv = 1.f / (red[4] + red[5] + red[6] + red[7]);
#pragma unroll
  for (int j = 0; j < 8; ++j) a_ws[b * Tt + threadIdx.x + 256 * j] = ev[j] * inv;
}

// ---------------- kernel 5a: partial c over 64-t chunks (deterministic) ----------------
__global__ __launch_bounds__(256) void k_c1(const float* __restrict__ h,
                                            const float* __restrict__ a_ws,
                                            float* __restrict__ cpart) {
  const int b  = blockIdx.x >> 5;
  const int tc = blockIdx.x & 31;
  const int t0 = tc << 6;
  __shared__ float a_sh[64];
  if (threadIdx.x < 64) a_sh[threadIdx.x] = a_ws[b * Tt + t0 + threadIdx.x];
  __syncthreads();
  f32x4 acc = {0.f, 0.f, 0.f, 0.f};
  const float* hb = h + ((size_t)b * Tt + t0) * Dd + threadIdx.x * 4;
#pragma unroll 4
  for (int t = 0; t < 64; ++t) {
    const f32x4 hv = *(const f32x4*)(hb + (size_t)t * Dd);
    acc += a_sh[t] * hv;
  }
  *(f32x4*)(cpart + ((size_t)(tc * 32 + b) << 10) + threadIdx.x * 4) = acc;
}

// ---------------- kernel 5b: reduce partials, store f32 ----------------
__global__ __launch_bounds__(256) void k_c2(const float* __restrict__ cpart,
                                            float* __restrict__ out) {
  const int gid = blockIdx.x * 256 + threadIdx.x;   // 0..32767
  const int b = gid >> 10;
  const int d = gid & 1023;
  float sv = 0.f;
#pragma unroll
  for (int tc = 0; tc < 32; ++tc) sv += cpart[((size_t)(tc * 32 + b) << 10) + d];
  out[gid] = sv;
}

extern "C" void kernel_launch(void* const* d_in, const int* in_sizes, int n_in,
                              void* d_out, int out_size, void* d_ws, size_t ws_size,
                              hipStream_t stream) {
  (void)in_sizes; (void)n_in; (void)out_size; (void)ws_size;
  const float* s  = (const float*)d_in[0];
  const float* h  = (const float*)d_in[1];
  const float* W  = (const float*)d_in[2];
  const float* U  = (const float*)d_in[3];
  const float* v  = (const float*)d_in[4];
  uint8_t* ws = (uint8_t*)d_ws;
  float*   w2_ws  = (float*)ws;
  float*   a_ws   = (float*)(ws + WS_A);
  float*   e_part = (float*)(ws + WS_EP);   // aliases cpart (sequential lifetimes)
  float*   cpart  = (float*)(ws + WS_EP);
  uint8_t* U_ts   = ws + WS_UT;

  k_ws<<<128, 256, 0, stream>>>(s, W, w2_ws);
  k_ut<<<256, 256, 0, stream>>>(U, U_ts);
  k_e <<<4096, 256, 0, stream>>>(h, U_ts, w2_ws, v, e_part);
  k_sm<<<Bb, 256, 0, stream>>>(e_part, a_ws);
  k_c1<<<1024, 256, 0, stream>>>(h, a_ws, cpart);
  k_c2<<<128, 256, 0, stream>>>(cpart, (float*)d_out);
}

// Round 11
// 296.425 us; speedup vs baseline: 1.7677x; 1.7677x over previous
//
#include <hip/hip_runtime.h>
#include <hip/hip_bf16.h>
#include <stdint.h>

#define Bb 32
#define Tt 2048
#define Dd 1024   // D_IN = D_H = D_OUT

typedef float    f32x4 __attribute__((ext_vector_type(4)));
typedef _Float16 f16x8 __attribute__((ext_vector_type(8)));
typedef uint32_t u32;

// ---- ws layout (bytes) ----
// 0        w2_ws  [32][1024] f32  (2 * s.W_a)          128K
// 131072   a_ws   [32][2048] f32                       256K
// 393216   UNION: e_part [8 ob][32 b][2048 t] f32 (2M, k_e->k_sm)
//                 cpart  [32 tc][32 b][1024] f32 (4M, k_c1->k_c2)
// 4587520  U_ts   tiled fp16 U^T (see k_ut)            2M
#define WS_A     131072
#define WS_EP    393216
#define WS_UT    4587520

__device__ __forceinline__ void gll16(const void* g, const void* lds) {
  __builtin_amdgcn_global_load_lds(
      (const __attribute__((address_space(1))) u32*)(uintptr_t)g,
      (__attribute__((address_space(3))) u32*)(uint32_t)(uintptr_t)lds,
      16, 0, 0);
}

// ---------------- kernel 1: w2[b][o] = 2 * sum_i s[b][i] * W[i][o] ----------------
__global__ __launch_bounds__(256) void k_ws(const float* __restrict__ s,
                                            const float* __restrict__ W,
                                            float* __restrict__ w2_ws) {
  const int b = blockIdx.x >> 2;
  const int o = (blockIdx.x & 3) * 256 + threadIdx.x;
  __shared__ float s_sh[Dd];
#pragma unroll
  for (int j = 0; j < 4; ++j)
    s_sh[threadIdx.x + 256 * j] = s[b * Dd + threadIdx.x + 256 * j];
  __syncthreads();
  float acc = 0.f;
#pragma unroll 8
  for (int i = 0; i < Dd; ++i) acc += s_sh[i] * W[(size_t)i * Dd + o];
  w2_ws[b * Dd + o] = 2.f * acc;
}

// ------- kernel 2: build U_ts, tile-major linear-lane layout -------
// Tile (ob, ks) = 16KB at (ob*16+ks)*16384; element (o_l, k_l):
// byte = (k_l>>5)*8192 + (o_l>>6)*4096 + ((o_l>>4)&3)*1024
//        + (((k_l>>3)&3)*16 + (o_l&15))*16 + (k_l&7)*2
__global__ __launch_bounds__(256) void k_ut(const float* __restrict__ U,
                                            uint8_t* __restrict__ U_ts) {
  const int i0 = (blockIdx.x >> 4) * 64;   // k-tile
  const int o0 = (blockIdx.x & 15) * 64;   // o-tile
  __shared__ float tile[64][65];           // [o_loc][k_loc]
  const int tx = threadIdx.x & 63;
  const int ty = threadIdx.x >> 6;
#pragma unroll
  for (int jj = 0; jj < 16; ++jj)
    tile[tx][ty + 4 * jj] = U[(size_t)(i0 + ty + 4 * jj) * Dd + o0 + tx];
  __syncthreads();
#pragma unroll
  for (int it = 0; it < 2; ++it) {
    const int g  = it * 256 + threadIdx.x;  // 0..511
    const int ol = g & 63;
    const int kg = g >> 6;                  // 0..7
    const int o  = o0 + ol;
    const int k  = i0 + kg * 8;
    f16x8 r;
#pragma unroll
    for (int m = 0; m < 8; ++m) r[m] = (_Float16)tile[ol][kg * 8 + m];
    const int ob  = o >> 7, ks = k >> 6;
    const int o_l = o & 127, k_l = k & 63;
    const size_t byte = ((size_t)(ob * 16 + ks) << 14)
                      + (size_t)((k_l >> 5) * 8192 + (o_l >> 6) * 4096
                      + ((o_l >> 4) & 3) * 1024
                      + (((k_l >> 3) & 3) * 16 + (o_l & 15)) * 16);
    *(f16x8*)(U_ts + byte) = r;
  }
}

// ---------------- kernel 3: fused GEMM, spill-free deep pipeline ----------------
// 128t x 128o per block, BK=64 x 16 steps, 4 waves, acc[4][4].
// A: gll16 double-buffer (zero regs). B: loads issued in-step BEFORE A's gll16,
// converted to fp16 AFTER the MFMA block (latency hidden under MFMA issue);
// only pk[4] f16x8 (8 regs) lives across steps. Barrier path has no load wait:
// vmcnt(12) = "everything older than this step's 12 new vmem ops retired"
// => A(KS) DMA landed. ds_write swizzle (t15 ^= tid&7): 0 bank conflicts.
__global__ __launch_bounds__(256, 3) void k_e(const float* __restrict__ h,
                                              const uint8_t* __restrict__ U_ts,
                                              const float* __restrict__ w2_ws,
                                              const float* __restrict__ v_a,
                                              float* __restrict__ e_part) {
  const int blk = blockIdx.x;
  const int b   = blk >> 7;
  const int ob  = (blk >> 4) & 7;
  const int tb  = blk & 15;
  const int tid  = threadIdx.x;
  const int lane = tid & 63;
  const int w    = tid >> 6;
  const int hw   = w & 1;    // o-half
  const int tw   = w >> 1;   // t-half

  __shared__ __align__(16) uint8_t Al[2][16384];
  __shared__ __align__(16) uint8_t Bl[16384];
  __shared__ float w_sh[128], v_sh[128], exch[128];

  // B global-load / swizzled LDS-write addressing
  const float* hrow = h + ((size_t)(b * Tt + tb * 128 + (tid >> 3))) * Dd + (tid & 7) * 8;
  int baddr[4];
  {
    const int kk  = (tid & 7) >> 2;
    const int klo = (tid & 7) & 3;
    const int cw  = tid & 7;
#pragma unroll
    for (int j = 0; j < 4; ++j) {
      const int t_l = (tid >> 3) + 32 * j;
      baddr[j] = kk * 8192 + (t_l >> 6) * 4096 + ((t_l >> 4) & 3) * 1024
               + (klo * 16 + ((t_l & 15) ^ cw)) * 16;
    }
  }
  // B read slots (swizzle-matched): kk=0 and kk=1
  const int klo_r = lane >> 4;
  const int rs0 = (klo_r * 16 + ((lane & 15) ^ klo_r)) * 16;
  const int rs1 = (klo_r * 16 + ((lane & 15) ^ klo_r ^ 4)) * 16;
  const uint8_t* Ub = U_ts + ((size_t)(ob * 16) << 14);

  f32x4 acc[4][4] = {};
  f32x4 br[8];
  f16x8 pk[4];

  // ---- prologue: w/v to LDS; B(0) loads; A(0) DMA; cvt pk(0) ----
  if (tid < 128) {
    w_sh[tid] = w2_ws[b * Dd + ob * 128 + tid];
    v_sh[tid] = v_a[ob * 128 + tid];
  }
#pragma unroll
  for (int j = 0; j < 4; ++j) {
    const float* p = hrow + (size_t)j * 32 * Dd;
    br[2 * j]     = *(const f32x4*)p;
    br[2 * j + 1] = *(const f32x4*)(p + 4);
  }
  {
    const uint8_t* As = Ub + (size_t)tid * 16;
    gll16(As,         &Al[0][w * 1024]);
    gll16(As + 4096,  &Al[0][w * 1024 + 4096]);
    gll16(As + 8192,  &Al[0][w * 1024 + 8192]);
    gll16(As + 12288, &Al[0][w * 1024 + 12288]);
  }
#pragma unroll
  for (int j = 0; j < 4; ++j) {   // compiler waits br (vmcnt(4): A(0) may stay in flight)
    f16x8 t;
#pragma unroll
    for (int m2 = 0; m2 < 4; ++m2) {
      t[m2]     = (_Float16)br[2 * j][m2];
      t[4 + m2] = (_Float16)br[2 * j + 1][m2];
    }
    pk[j] = t;
  }
  asm volatile("s_waitcnt lgkmcnt(0)" ::: "memory");  // w_sh/v_sh visible at 1st barrier

// STEP(KS): B1; ds_write pk(KS); issue B(KS+1); issue A(KS+1); lgkm; VMC; B2;
//           MFMA(KS) on Al[CUR]+Bl; [sched fence] cvt br -> pk(KS+1).
#define STEP(KS, CUR, PRE, VMC)                                               \
  {                                                                           \
    __builtin_amdgcn_sched_barrier(0);                                        \
    __builtin_amdgcn_s_barrier();            /* B1: plain, no drains */       \
    __builtin_amdgcn_sched_barrier(0);                                        \
    _Pragma("unroll")                                                         \
    for (int j = 0; j < 4; ++j) *(f16x8*)(Bl + baddr[j]) = pk[j];             \
    if (PRE) {                                                                \
      _Pragma("unroll")                      /* B loads first (older) */      \
      for (int j = 0; j < 4; ++j) {                                           \
        const float* p = hrow + (size_t)j * 32 * Dd + ((KS) + 1) * 64;        \
        br[2 * j]     = *(const f32x4*)p;                                     \
        br[2 * j + 1] = *(const f32x4*)(p + 4);                               \
      }                                                                       \
      const uint8_t* As = Ub + ((size_t)((KS) + 1) << 14) + (size_t)tid * 16; \
      gll16(As,         &Al[(CUR) ^ 1][w * 1024]);                            \
      gll16(As + 4096,  &Al[(CUR) ^ 1][w * 1024 + 4096]);                     \
      gll16(As + 8192,  &Al[(CUR) ^ 1][w * 1024 + 8192]);                     \
      gll16(As + 12288, &Al[(CUR) ^ 1][w * 1024 + 12288]);                    \
    }                                                                         \
    asm volatile("s_waitcnt lgkmcnt(0)" ::: "memory");  /* ds_writes done */  \
    asm volatile(VMC ::: "memory");          /* A(KS) DMA landed */           \
    __builtin_amdgcn_sched_barrier(0);                                        \
    __builtin_amdgcn_s_barrier();            /* B2 */                         \
    __builtin_amdgcn_sched_barrier(0);                                        \
    _Pragma("unroll")                                                         \
    for (int kk = 0; kk < 2; ++kk) {                                          \
      f16x8 af[4], bf[4];                                                     \
      _Pragma("unroll")                                                       \
      for (int n = 0; n < 4; ++n)                                             \
        af[n] = *(const f16x8*)(&Al[CUR][0] + kk * 8192 + hw * 4096           \
                                + n * 1024 + lane * 16);                      \
      _Pragma("unroll")                                                       \
      for (int m = 0; m < 4; ++m)                                             \
        bf[m] = *(const f16x8*)(Bl + kk * 8192 + tw * 4096 + m * 1024         \
                                + (kk ? rs1 : rs0));                          \
      _Pragma("unroll")                                                       \
      for (int m = 0; m < 4; ++m)                                             \
        _Pragma("unroll")                                                     \
        for (int n = 0; n < 4; ++n)                                           \
          acc[m][n] = __builtin_amdgcn_mfma_f32_16x16x32_f16(af[n], bf[m],    \
                                                             acc[m][n], 0, 0, 0); \
    }                                                                         \
    if (PRE) {                               /* cvt AFTER MFMA (hidden) */    \
      __builtin_amdgcn_sched_barrier(0);                                      \
      _Pragma("unroll")                                                       \
      for (int j = 0; j < 4; ++j) {                                           \
        f16x8 t;                                                              \
        _Pragma("unroll")                                                     \
        for (int m2 = 0; m2 < 4; ++m2) {                                      \
          t[m2]     = (_Float16)br[2 * j][m2];                                \
          t[4 + m2] = (_Float16)br[2 * j + 1][m2];                            \
        }                                                                     \
        pk[j] = t;                                                            \
      }                                                                       \
    }                                                                         \
  }

#pragma unroll 1
  for (int ks2 = 0; ks2 < 7; ++ks2) {   // steps 0..13
    const int ks = ks2 * 2;
    STEP(ks,     0, 1, "s_waitcnt vmcnt(12)")
    STEP(ks + 1, 1, 1, "s_waitcnt vmcnt(12)")
  }
  STEP(14, 0, 1, "s_waitcnt vmcnt(12)")
  STEP(15, 1, 0, "s_waitcnt vmcnt(0)")
#undef STEP

  // epilogue (once per block): tanh + v-weight + reduce over o
  float ep[4] = {0.f, 0.f, 0.f, 0.f};
#pragma unroll
  for (int m = 0; m < 4; ++m)
#pragma unroll
    for (int n = 0; n < 4; ++n)
#pragma unroll
      for (int r = 0; r < 4; ++r) {
        const int o_loc = hw * 64 + n * 16 + ((lane >> 4) << 2) + r;
        const float x = __builtin_fmaf(acc[m][n][r], 2.f, w_sh[o_loc]);
        ep[m] += v_sh[o_loc] * (1.f - 2.f / (__expf(x) + 1.f));
      }
#pragma unroll
  for (int m = 0; m < 4; ++m) {
    ep[m] += __shfl_xor(ep[m], 16, 64);
    ep[m] += __shfl_xor(ep[m], 32, 64);
  }
  __syncthreads();
  if (hw == 1 && lane < 16) {
#pragma unroll
    for (int m = 0; m < 4; ++m) exch[tw * 64 + m * 16 + lane] = ep[m];
  }
  __syncthreads();
  if (hw == 0 && lane < 16) {
#pragma unroll
    for (int m = 0; m < 4; ++m) {
      const int t_loc = tw * 64 + m * 16 + lane;
      e_part[((size_t)(ob * Bb + b)) * Tt + tb * 128 + t_loc] = ep[m] + exch[t_loc];
    }
  }
}

// ---------------- kernel 4: reduce 8 o-partials + softmax over T per b ----------------
__global__ __launch_bounds__(256) void k_sm(const float* __restrict__ e_part,
                                            float* __restrict__ a_ws) {
  const int b = blockIdx.x;
  const int lane = threadIdx.x & 63;
  const int wv = threadIdx.x >> 6;
  __shared__ float red[8];
  float ev[8];
  float m = -1e30f;
#pragma unroll
  for (int j = 0; j < 8; ++j) {
    const int t = threadIdx.x + 256 * j;
    float sv = 0.f;
#pragma unroll
    for (int o = 0; o < 8; ++o) sv += e_part[((size_t)(o * Bb + b)) * Tt + t];
    ev[j] = sv;
    m = fmaxf(m, sv);
  }
#pragma unroll
  for (int sft = 1; sft < 64; sft <<= 1) m = fmaxf(m, __shfl_xor(m, sft, 64));
  if (lane == 0) red[wv] = m;
  __syncthreads();
  m = fmaxf(fmaxf(red[0], red[1]), fmaxf(red[2], red[3]));
  float sum = 0.f;
#pragma unroll
  for (int j = 0; j < 8; ++j) { ev[j] = __expf(ev[j] - m); sum += ev[j]; }
#pragma unroll
  for (int sft = 1; sft < 64; sft <<= 1) sum += __shfl_xor(sum, sft, 64);
  if (lane == 0) red[4 + wv] = sum;
  __syncthreads();
  const float inv = 1.f / (red[4] + red[5] + red[6] + red[7]);
#pragma unroll
  for (int j = 0; j < 8; ++j) a_ws[b * Tt + threadIdx.x + 256 * j] = ev[j] * inv;
}

// ---------------- kernel 5a: partial c over 64-t chunks (deterministic) ----------------
__global__ __launch_bounds__(256) void k_c1(const float* __restrict__ h,
                                            const float* __restrict__ a_ws,
                                            float* __restrict__ cpart) {
  const int b  = blockIdx.x >> 5;
  const int tc = blockIdx.x & 31;
  const int t0 = tc << 6;
  __shared__ float a_sh[64];
  if (threadIdx.x < 64) a_sh[threadIdx.x] = a_ws[b * Tt + t0 + threadIdx.x];
  __syncthreads();
  f32x4 acc = {0.f, 0.f, 0.f, 0.f};
  const float* hb = h + ((size_t)b * Tt + t0) * Dd + threadIdx.x * 4;
#pragma unroll 4
  for (int t = 0; t < 64; ++t) {
    const f32x4 hv = *(const f32x4*)(hb + (size_t)t * Dd);
    acc += a_sh[t] * hv;
  }
  *(f32x4*)(cpart + ((size_t)(tc * 32 + b) << 10) + threadIdx.x * 4) = acc;
}

// ---------------- kernel 5b: reduce partials, store f32 ----------------
__global__ __launch_bounds__(256) void k_c2(const float* __restrict__ cpart,
                                            float* __restrict__ out) {
  const int gid = blockIdx.x * 256 + threadIdx.x;   // 0..32767
  const int b = gid >> 10;
  const int d = gid & 1023;
  float sv = 0.f;
#pragma unroll
  for (int tc = 0; tc < 32; ++tc) sv += cpart[((size_t)(tc * 32 + b) << 10) + d];
  out[gid] = sv;
}

extern "C" void kernel_launch(void* const* d_in, const int* in_sizes, int n_in,
                              void* d_out, int out_size, void* d_ws, size_t ws_size,
                              hipStream_t stream) {
  (void)in_sizes; (void)n_in; (void)out_size; (void)ws_size;
  const float* s  = (const float*)d_in[0];
  const float* h  = (const float*)d_in[1];
  const float* W  = (const float*)d_in[2];
  const float* U  = (const float*)d_in[3];
  const float* v  = (const float*)d_in[4];
  uint8_t* ws = (uint8_t*)d_ws;
  float*   w2_ws  = (float*)ws;
  float*   a_ws   = (float*)(ws + WS_A);
  float*   e_part = (float*)(ws + WS_EP);   // aliases cpart (sequential lifetimes)
  float*   cpart  = (float*)(ws + WS_EP);
  uint8_t* U_ts   = ws + WS_UT;

  k_ws<<<128, 256, 0, stream>>>(s, W, w2_ws);
  k_ut<<<256, 256, 0, stream>>>(U, U_ts);
  k_e <<<4096, 256, 0, stream>>>(h, U_ts, w2_ws, v, e_part);
  k_sm<<<Bb, 256, 0, stream>>>(e_part, a_ws);
  k_c1<<<1024, 256, 0, stream>>>(h, a_ws, cpart);
  k_c2<<<128, 256, 0, stream>>>(cpart, (float*)d_out);
}